// Round 1
// 1020.645 us; speedup vs baseline: 1.3118x; 1.3118x over previous
//
#include <hip/hip_runtime.h>
#include <math.h>

#define DIM    1024
#define INNER  2048
#define BATCH  32
#define NCHUNK 16
#define CROWS  128   // INNER / NCHUNK rows per wsum block

__device__ __forceinline__ float4 f4add(float4 a, float4 b) {
    return make_float4(a.x + b.x, a.y + b.y, a.z + b.z, a.w + b.w);
}

// ---------------------------------------------------------------------------
// K1 (fused): blocks [0,512): colsum partials (no atomics) + rowsum over W.
//             blocks [512,1024): q/k/v GEMV (latency-bound, overlaps the
//             BW-bound W stream on the same CUs).
// wsum layout: 256 thr = 4 waves; each wave owns whole rows (2048 floats =
// 8 float4/lane) -> rowsum completes in-wave (6 shuffles per 8KB, not per
// 1KB as before); column sums accumulate vertically in 8 float4 registers,
// combined across the 4 waves via LDS, written as per-chunk partials.
// ---------------------------------------------------------------------------
__global__ __launch_bounds__(256) void pre_kernel(
    const float* __restrict__ x,
    const float* __restrict__ Wq, const float* __restrict__ bq,
    const float* __restrict__ Wk, const float* __restrict__ bk,
    const float* __restrict__ Wv, const float* __restrict__ bv,
    const float* __restrict__ W,
    float* __restrict__ q, float* __restrict__ k, float* __restrict__ v,
    float* __restrict__ colpart, float* __restrict__ rowsum)
{
    __shared__ float4 sh[4][512];   // 32 KB; qkv path reuses first 4 KB as xs
    const int bid = blockIdx.x;
    const int t   = threadIdx.x;

    if (bid < BATCH * NCHUNK) {
        // ---- wsum part ----
        const int b     = bid & (BATCH - 1);     // b fastest in dispatch order
        const int chunk = bid >> 5;
        const int i0    = chunk * CROWS;
        const int wave  = t >> 6, lane = t & 63;
        const float4* Wp = (const float4*)(W + (size_t)b * INNER * INNER);

        float4 csum[8];
        #pragma unroll
        for (int c = 0; c < 8; ++c) csum[c] = make_float4(0.f, 0.f, 0.f, 0.f);

        for (int r = wave; r < CROWS; r += 4) {
            const size_t rb = (size_t)(i0 + r) * (INNER / 4);
            float4 w4[8];
            #pragma unroll
            for (int c = 0; c < 8; ++c) w4[c] = Wp[rb + lane + 64 * c];
            #pragma unroll
            for (int c = 0; c < 8; ++c) csum[c] = f4add(csum[c], w4[c]);
            float4 racc = f4add(f4add(f4add(w4[0], w4[1]), f4add(w4[2], w4[3])),
                                f4add(f4add(w4[4], w4[5]), f4add(w4[6], w4[7])));
            float s = (racc.x + racc.y) + (racc.z + racc.w);
            #pragma unroll
            for (int m = 1; m < 64; m <<= 1) s += __shfl_xor(s, m, 64);
            if (lane == 0) rowsum[b * INNER + i0 + r] = s;
        }
        #pragma unroll
        for (int c = 0; c < 8; ++c) sh[wave][lane + 64 * c] = csum[c];
        __syncthreads();
        float4* cp = (float4*)colpart + (size_t)(b * NCHUNK + chunk) * (INNER / 4);
        #pragma unroll
        for (int c2 = 0; c2 < 2; ++c2) {
            const int c4 = t + 256 * c2;
            cp[c4] = f4add(f4add(sh[0][c4], sh[1][c4]), f4add(sh[2][c4], sh[3][c4]));
        }
    } else {
        // ---- qkv part ----
        const int idx = bid - BATCH * NCHUNK;
        const int b   = idx & (BATCH - 1);
        float* xs = (float*)sh;
        const float4* xsrc = (const float4*)(x + b * DIM);
        float4* xdst = (float4*)xs;
        for (int i = t; i < DIM / 4; i += 256) xdst[i] = xsrc[i];
        __syncthreads();

        const int c = (idx >> 5) * 256 + t;   // 0..4095: [q|k|v] virtual cols
        const float* Wm; const float* bias; float* outp; int N, n;
        if (c < DIM)          { Wm = Wq; bias = bq; outp = q; N = DIM;   n = c;           }
        else if (c < 2 * DIM) { Wm = Wk; bias = bk; outp = k; N = DIM;   n = c - DIM;     }
        else                  { Wm = Wv; bias = bv; outp = v; N = INNER; n = c - 2 * DIM; }

        float acc = 0.f;
        #pragma unroll 8
        for (int kk = 0; kk < DIM; ++kk)
            acc += xs[kk] * Wm[(size_t)kk * N + n];
        outp[(size_t)b * N + n] = acc + bias[n];
    }
}

// dpfp "concat(relu(k), relu(-k))" element (from an LDS-staged row)
__device__ __forceinline__ float xcf(const float* __restrict__ kb, int j) {
    float val = (j < DIM) ? kb[j] : -kb[j - DIM];
    return fmaxf(val, 0.f);
}

// ---------------------------------------------------------------------------
// K2: per-batch vector work + colsum partial reduction. One block per b.
// ---------------------------------------------------------------------------
__global__ __launch_bounds__(256) void vec_kernel(
    const float* __restrict__ x, const float* __restrict__ Wb, const float* __restrict__ bb,
    const float* __restrict__ q, const float* __restrict__ k, const float* __restrict__ v,
    const float* __restrict__ colpart, const float* __restrict__ rowsum,
    float* __restrict__ kp, float* __restrict__ dv, float* __restrict__ outv)
{
    __shared__ float kb_s[DIM], qb_s[DIM];
    __shared__ float red1[4], red2[4];
    const int b = blockIdx.x, t = threadIdx.x;
    const int wave = t >> 6, lane = t & 63;

    // stage k,q rows; accumulate beta dot in the same sweep
    const float* xrow = x + b * DIM;
    float bsum = 0.f;
    for (int i = t; i < DIM; i += 256) {
        kb_s[i] = k[b * DIM + i];
        qb_s[i] = q[b * DIM + i];
        bsum += xrow[i] * Wb[i];
    }
    #pragma unroll
    for (int m = 1; m < 64; m <<= 1) bsum += __shfl_xor(bsum, m, 64);
    if (lane == 0) red1[wave] = bsum;
    __syncthreads();
    const float beta = 1.f / (1.f + expf(-((red1[0] + red1[1] + red1[2] + red1[3]) + bb[0])));

    float skp = 0.f, dvu[8], ru[8];
    #pragma unroll
    for (int u = 0; u < 8; ++u) {
        const int j = u * 256 + t;
        float cs = 0.f;
        #pragma unroll
        for (int c = 0; c < NCHUNK; ++c)
            cs += colpart[(size_t)(b * NCHUNK + c) * INNER + j];
        const float kpj = xcf(kb_s, j) * xcf(kb_s, (j + INNER - 1) & (INNER - 1));
        kp[b * INNER + j] = kpj;
        skp += kpj;
        const float dvj = beta * (v[b * INNER + j] - cs * kpj);
        dvu[u] = dvj;
        dv[b * INNER + j] = dvj;
        ru[u] = rowsum[b * INNER + j];
    }
    #pragma unroll
    for (int m = 1; m < 64; m <<= 1) skp += __shfl_xor(skp, m, 64);
    if (lane == 0) red2[wave] = skp;
    __syncthreads();
    const float S = red2[0] + red2[1] + red2[2] + red2[3];

    #pragma unroll
    for (int u = 0; u < 8; ++u) {
        const int j = u * 256 + t;
        const float qpj = xcf(qb_s, j) * xcf(qb_s, (j + INNER - 1) & (INNER - 1));
        outv[b * INNER + j] = (ru[u] + dvu[u] * S) * qpj;
    }
}

// ---------------------------------------------------------------------------
// K3 (fused): blocks [0,512): out = outv @ Wo + bo (64 cols/block, wave-per-
//             i-range, 256B coalesced Wo loads). blocks [512,512+65536):
//             Wn row update, one (b,i) row per block, 2 float4/thread.
// The latency-bound GEMV overlaps the 1 GB Wn stream.
// ---------------------------------------------------------------------------
__global__ __launch_bounds__(256) void post_kernel(
    const float* __restrict__ outv, const float* __restrict__ Wo,
    const float* __restrict__ bo, float* __restrict__ out,
    const float* __restrict__ W, const float* __restrict__ dv,
    const float* __restrict__ kp, float* __restrict__ Wn)
{
    const int bid = blockIdx.x;
    const int t   = threadIdx.x;
    if (bid < 512) {
        __shared__ float os[INNER];
        __shared__ float part[4][64];
        const int b    = bid & (BATCH - 1);
        const int n0   = (bid >> 5) * 64;
        const int wave = t >> 6, lane = t & 63;

        const float4* src = (const float4*)(outv + b * INNER);
        float4* dst = (float4*)os;
        for (int i = t; i < INNER / 4; i += 256) dst[i] = src[i];
        __syncthreads();

        const float* Wcol = Wo + n0 + lane;
        const int ibase = wave * 512;
        float acc = 0.f;
        #pragma unroll 8
        for (int i = 0; i < 512; ++i)
            acc += os[ibase + i] * Wcol[(size_t)(ibase + i) * DIM];
        part[wave][lane] = acc;
        __syncthreads();
        if (t < 64)
            out[b * DIM + n0 + t] =
                ((part[0][t] + part[1][t]) + (part[2][t] + part[3][t])) + bo[n0 + t];
    } else {
        const int wb = bid - 512;          // global row index = b*2048 + i
        const int b  = wb >> 11;
        const float d = dv[wb];            // uniform per block
        const float4* kp4 = (const float4*)(kp + b * INNER);
        const float4* Wr  = (const float4*)W  + ((size_t)wb << 9);
        float4*       Wnr = (float4*)Wn       + ((size_t)wb << 9);
        float4 w0 = Wr[t],       k0 = kp4[t];
        float4 w1 = Wr[t + 256], k1 = kp4[t + 256];
        w0.x += d * k0.x; w0.y += d * k0.y; w0.z += d * k0.z; w0.w += d * k0.w;
        w1.x += d * k1.x; w1.y += d * k1.y; w1.z += d * k1.z; w1.w += d * k1.w;
        Wnr[t]       = w0;
        Wnr[t + 256] = w1;
    }
}

// ---------------------------------------------------------------------------
extern "C" void kernel_launch(void* const* d_in, const int* in_sizes, int n_in,
                              void* d_out, int out_size, void* d_ws, size_t ws_size,
                              hipStream_t stream)
{
    const float* x  = (const float*)d_in[0];
    const float* W  = (const float*)d_in[1];
    const float* Wq = (const float*)d_in[2];
    const float* bq = (const float*)d_in[3];
    const float* Wk = (const float*)d_in[4];
    const float* bk = (const float*)d_in[5];
    const float* Wv = (const float*)d_in[6];
    const float* bv = (const float*)d_in[7];
    const float* Wo = (const float*)d_in[8];
    const float* bo = (const float*)d_in[9];
    const float* Wb = (const float*)d_in[10];
    const float* bb = (const float*)d_in[11];

    float* out = (float*)d_out;                          // [32,1024]
    float* Wn  = (float*)d_out + (size_t)BATCH * DIM;    // [32,2048,2048]

    float* ws = (float*)d_ws;
    float* q       = ws;                        // 32*1024
    float* k       = q + BATCH * DIM;           // 32*1024
    float* v       = k + BATCH * DIM;           // 32*2048
    float* rowsum  = v + BATCH * INNER;         // 32*2048
    float* kp      = rowsum + BATCH * INNER;    // 32*2048
    float* dv      = kp + BATCH * INNER;        // 32*2048
    float* outv    = dv + BATCH * INNER;        // 32*2048
    float* colpart = outv + BATCH * INNER;      // 32*16*2048 = 4 MB

    pre_kernel<<<dim3(BATCH * NCHUNK + 512), 256, 0, stream>>>(
        x, Wq, bq, Wk, bk, Wv, bv, W, q, k, v, colpart, rowsum);
    vec_kernel<<<dim3(BATCH), 256, 0, stream>>>(
        x, Wb, bb, q, k, v, colpart, rowsum, kp, dv, outv);
    post_kernel<<<dim3(512 + BATCH * INNER), 256, 0, stream>>>(
        outv, Wo, bo, out, W, dv, kp, Wn);
}